// Round 5
// baseline (5433.385 us; speedup 1.0000x reference)
//
#include <hip/hip_runtime.h>

#define DI __device__ __forceinline__

// One block per batch element. 256 threads; thread tid owns hidden column tid.
// Pure f32 scalar math; LDS holds h[20][256], t[20][256], msg/g/q/r vectors.
// d_out is FLOAT32 (reference computes in f32): layout [oh B*8 | c1 B*10 | c2 B*10 | pl B*20].
__global__ __launch_bounds__(256) void simple_graphnet(
    const float* __restrict__ nf, const int* __restrict__ nn_c,
    const float* __restrict__ neW, const float* __restrict__ neb,
    const float* __restrict__ g1W1, const float* __restrict__ g1b1,
    const float* __restrict__ g1W2, const float* __restrict__ g1b2,
    const float* __restrict__ g2W1, const float* __restrict__ g2b1,
    const float* __restrict__ g2W2, const float* __restrict__ g2b2,
    const float* __restrict__ n1g, const float* __restrict__ n1b,
    const float* __restrict__ n2g, const float* __restrict__ n2b,
    const float* __restrict__ ohW, const float* __restrict__ ohb,
    const float* __restrict__ c1W, const float* __restrict__ c1b,
    const float* __restrict__ c2W, const float* __restrict__ c2b,
    const float* __restrict__ pqW, const float* __restrict__ pqb,
    const float* __restrict__ pkW, const float* __restrict__ pkb,
    float* __restrict__ out, int out_n)
{
  __shared__ float h[20][256];
  __shared__ float t[20][256];
  __shared__ float msg[256];
  __shared__ float gs[256];
  __shared__ float qs[256];
  __shared__ float rs[256];
  __shared__ float red[8];

  const int b = blockIdx.x;
  const int tid = threadIdx.x;
  const int Bout = out_n / 48;           // 8 + 10 + 10 + 20 outputs per batch
  const int off_c1 = 8 * Bout;
  const int off_c2 = 18 * Bout;
  const int off_pl = 28 * Bout;

  int cnt = nn_c[b];
  cnt = cnt < 0 ? 0 : (cnt > 20 ? 20 : cnt);
  const float dinv = 1.0f / (float)(cnt < 1 ? 1 : cnt);

  // --- h = nf @ neW + neb ---
  {
    float acc[20];
#pragma unroll
    for (int n = 0; n < 20; n++) acc[n] = 0.0f;
    for (int k = 0; k < 16; k++){
      float w = neW[k * 256 + tid];
#pragma unroll
      for (int n = 0; n < 20; n++) acc[n] += nf[(b * 20 + n) * 16 + k] * w;
    }
    float bb = neb[tid];
#pragma unroll
    for (int n = 0; n < 20; n++) h[n][tid] = acc[n] + bb;
  }
  __syncthreads();

  for (int rd = 0; rd < 2; rd++){
    const float* W1 = rd ? g2W1 : g1W1;   // [512][256] row-major
    const float* W2 = rd ? g2W2 : g1W2;   // [256][256]
    const float* b1 = rd ? g2b1 : g1b1;
    const float* b2 = rd ? g2b2 : g1b2;
    const float* ng = rd ? n2g : n1g;
    const float* nb = rd ? n2b : n1b;

    // msg = masked mean of h rows
    {
      float s = 0.0f;
      for (int n = 0; n < cnt; n++) s += h[n][tid];
      msg[tid] = s * dinv;
    }
    __syncthreads();

    // pb = msg @ W1[256:512] + b1   (per-thread column, register)
    float pb;
    {
      float acc = 0.0f;
      for (int k = 0; k < 256; k++) acc += msg[k] * W1[(256 + k) * 256 + tid];
      pb = acc + b1[tid];
    }

    // t = relu(h @ W1[0:256] + pb)
    {
      float acc[20];
#pragma unroll
      for (int n = 0; n < 20; n++) acc[n] = 0.0f;
      for (int k = 0; k < 256; k++){
        float w = W1[k * 256 + tid];
#pragma unroll
        for (int n = 0; n < 20; n++) acc[n] += h[n][k] * w;
      }
#pragma unroll
      for (int n = 0; n < 20; n++) t[n][tid] = fmaxf(acc[n] + pb, 0.0f);
    }
    __syncthreads();

    // h += t @ W2 + b2
    {
      float acc[20];
#pragma unroll
      for (int n = 0; n < 20; n++) acc[n] = 0.0f;
      for (int k = 0; k < 256; k++){
        float w = W2[k * 256 + tid];
#pragma unroll
        for (int n = 0; n < 20; n++) acc[n] += t[n][k] * w;
      }
      float bb = b2[tid];
#pragma unroll
      for (int n = 0; n < 20; n++) h[n][tid] += acc[n] + bb;
    }
    __syncthreads();

    // LayerNorm per row, then *mask
    {
      float ngv = ng[tid], nbv = nb[tid];
      for (int n = 0; n < 20; n++){
        float v = h[n][tid];
        float s1 = v, s2 = v * v;
#pragma unroll
        for (int d = 1; d < 64; d <<= 1){
          s1 += __shfl_xor(s1, d, 64);
          s2 += __shfl_xor(s2, d, 64);
        }
        if ((tid & 63) == 0){ red[tid >> 6] = s1; red[4 + (tid >> 6)] = s2; }
        __syncthreads();
        float m   = (red[0] + red[1] + red[2] + red[3]) * (1.0f / 256.0f);
        float var = (red[4] + red[5] + red[6] + red[7]) * (1.0f / 256.0f) - m * m;
        float rstd = rsqrtf(fmaxf(var, 0.0f) + 1e-5f);
        float mf = (n < cnt) ? 1.0f : 0.0f;
        __syncthreads();   // red consumed before next row overwrites
        h[n][tid] = ((v - m) * rstd * ngv + nbv) * mf;
      }
    }
    __syncthreads();
  }

  // g = masked mean of final h
  {
    float s = 0.0f;
    for (int n = 0; n < cnt; n++) s += h[n][tid];
    gs[tid] = s * dinv;
  }
  __syncthreads();

  // q = g @ pqW + pqb
  {
    float acc = 0.0f;
    for (int k = 0; k < 256; k++) acc += gs[k] * pqW[k * 256 + tid];
    qs[tid] = acc + pqb[tid];
  }
  __syncthreads();

  // r[j] = sum_h pkW[j,h] * q[h]   (pl = h . r + q.pkb)
  {
    float acc = 0.0f;
    for (int k = 0; k < 256; k++) acc += qs[k] * pkW[tid * 256 + k];
    rs[tid] = acc;
  }
  // qdot = q . pkb
  float qd;
  {
    float p = qs[tid] * pkb[tid];
#pragma unroll
    for (int d = 1; d < 64; d <<= 1) p += __shfl_xor(p, d, 64);
    if ((tid & 63) == 0) red[tid >> 6] = p;
    __syncthreads();   // also publishes rs[] for the pl phase
    qd = red[0] + red[1] + red[2] + red[3];
    __syncthreads();
  }

  // pl[b,n] = h[n] . r + qd, masked -> exactly -1e9
  for (int n = 0; n < 20; n++){
    float p = h[n][tid] * rs[tid];
#pragma unroll
    for (int d = 1; d < 64; d <<= 1) p += __shfl_xor(p, d, 64);
    if ((tid & 63) == 0) red[tid >> 6] = p;
    __syncthreads();
    if (tid == 0){
      float s = red[0] + red[1] + red[2] + red[3];
      float v = (n < cnt) ? (s + qd) : -1e9f;
      int idx = off_pl + b * 20 + n;
      if (idx < out_n) out[idx] = v;
    }
    __syncthreads();
  }

  // heads: oh [B,8]@0, c1 [B,10]@off_c1, c2 [B,10]@off_c2
  if (tid < 28){
    const float* W; const float* bias; int ncol, col, off;
    if (tid < 8)      { W = ohW; bias = ohb; ncol = 8;  col = tid;      off = 0; }
    else if (tid < 18){ W = c1W; bias = c1b; ncol = 10; col = tid - 8;  off = off_c1; }
    else              { W = c2W; bias = c2b; ncol = 10; col = tid - 18; off = off_c2; }
    float acc = bias[col];
    for (int k = 0; k < 256; k++) acc += gs[k] * W[k * ncol + col];
    int idx = off + b * ncol + col;
    if (idx < out_n) out[idx] = acc;
  }
}

extern "C" void kernel_launch(void* const* d_in, const int* in_sizes, int n_in,
                              void* d_out, int out_size, void* d_ws, size_t ws_size,
                              hipStream_t stream)
{
  const float* nf   = (const float*)d_in[0];
  const int*   nn_c = (const int*)d_in[1];
  const float* neW  = (const float*)d_in[2];
  const float* neb  = (const float*)d_in[3];
  const float* g1W1 = (const float*)d_in[4];
  const float* g1b1 = (const float*)d_in[5];
  const float* g1W2 = (const float*)d_in[6];
  const float* g1b2 = (const float*)d_in[7];
  const float* g2W1 = (const float*)d_in[8];
  const float* g2b1 = (const float*)d_in[9];
  const float* g2W2 = (const float*)d_in[10];
  const float* g2b2 = (const float*)d_in[11];
  const float* n1g  = (const float*)d_in[12];
  const float* n1b  = (const float*)d_in[13];
  const float* n2g  = (const float*)d_in[14];
  const float* n2b  = (const float*)d_in[15];
  const float* ohW  = (const float*)d_in[16];
  const float* ohb  = (const float*)d_in[17];
  const float* c1W  = (const float*)d_in[18];
  const float* c1b  = (const float*)d_in[19];
  const float* c2W  = (const float*)d_in[20];
  const float* c2b  = (const float*)d_in[21];
  const float* pqW  = (const float*)d_in[22];
  const float* pqb  = (const float*)d_in[23];
  const float* pkW  = (const float*)d_in[24];
  const float* pkb  = (const float*)d_in[25];

  float* outp = (float*)d_out;
  int B = in_sizes[0] / 320;   // nf is [B,20,16]

  simple_graphnet<<<B, 256, 0, stream>>>(
      nf, nn_c, neW, neb, g1W1, g1b1, g1W2, g1b2, g2W1, g2b1, g2W2, g2b2,
      n1g, n1b, n2g, n2b, ohW, ohb, c1W, c1b, c2W, c2b, pqW, pqb, pkW, pkb,
      outp, out_size);
}

// Round 6
// 2019.034 us; speedup vs baseline: 2.6911x; 2.6911x over previous
//
#include <hip/hip_runtime.h>

typedef unsigned short ushort_t;
using short8 = __attribute__((ext_vector_type(8))) short;
using f32x4  = __attribute__((ext_vector_type(4))) float;

#define DI __device__ __forceinline__

DI ushort_t f2bf(float f){
  union { float f; unsigned u; } v; v.f = f;
  unsigned u = v.u;
  return (ushort_t)((u + 0x7FFFu + ((u >> 16) & 1u)) >> 16);
}
DI float bf2f(ushort_t u){
  union { unsigned u; float f; } v; v.u = ((unsigned)u) << 16;
  return v.f;
}

DI f32x4 MFMA(short8 a, short8 b, f32x4 c){
  return __builtin_amdgcn_mfma_f32_16x16x32_bf16(a, b, c, 0, 0, 0);
}

// swizzled LDS bf16 tile addressing; row stride 256 elems (512B)
DI int swzi(int row, int col){
  int byte = (row << 9) + (col << 1);
  byte ^= (row & 7) << 4;
  return byte >> 1;
}
DI short8 ldsA(const ushort_t* buf, int row, int k0){
  return *(const short8*)(buf + swzi(row, k0));
}
DI short8 ldG(const ushort_t* p){ return *(const short8*)p; }

// fallback B-fragment builders from f32 global (used when ws too small)
DI short8 loadWT(const float* __restrict__ W, int n, int k0){
  short8 s;
#pragma unroll
  for (int j = 0; j < 8; j++) s[j] = (short)f2bf(W[(k0 + j) * 256 + n]);
  return s;
}
DI short8 loadWT16(const float* __restrict__ W, int n, int k0){
  short8 s;
#pragma unroll
  for (int j = 0; j < 8; j++){
    int k = k0 + j;
    s[j] = (short)((k < 16) ? f2bf(W[k * 256 + n]) : 0);
  }
  return s;
}
DI short8 loadWrow(const float* __restrict__ W, int n, int k0){
  short8 s;
#pragma unroll
  for (int j = 0; j < 8; j++) s[j] = (short)f2bf(W[n * 256 + k0 + j]);
  return s;
}

// d_ws layout (ushort indices)
#define WS_NEWT  0        // [256][32]  neW^T, K padded 16->32
#define WS_W1AT1 8192     // [256][256] g1W1[0:256]^T
#define WS_W1BT1 73728    // [256][256] g1W1[256:512]^T
#define WS_W2T1  139264   // [256][256] g1W2^T
#define WS_W1AT2 204800
#define WS_W1BT2 270336
#define WS_W2T2  335872
#define WS_PQWT  401408   // [256][256] pqW^T
#define WS_PKWP  466944   // [256][256] pkW plain copy (acts as B^T for r-GEMM)
#define WS_TOTAL 532480
#define WS_BYTES (WS_TOTAL * 2)

__global__ void prep_weights(
    const float* __restrict__ neW, const float* __restrict__ g1W1,
    const float* __restrict__ g1W2, const float* __restrict__ g2W1,
    const float* __restrict__ g2W2, const float* __restrict__ pqW,
    const float* __restrict__ pkW, ushort_t* __restrict__ ws)
{
  int i = blockIdx.x * 256 + threadIdx.x;
  if (i >= WS_TOTAL) return;
  float v;
  if (i < 8192){
    int n = i >> 5, k = i & 31;
    v = (k < 16) ? neW[k * 256 + n] : 0.0f;
  } else {
    int j = i - 8192;
    int region = j >> 16;
    int idx = j & 65535;
    int n = idx >> 8, k = idx & 255;
    switch (region){
      case 0: v = g1W1[k * 256 + n]; break;
      case 1: v = g1W1[(256 + k) * 256 + n]; break;
      case 2: v = g1W2[k * 256 + n]; break;
      case 3: v = g2W1[k * 256 + n]; break;
      case 4: v = g2W1[(256 + k) * 256 + n]; break;
      case 5: v = g2W2[k * 256 + n]; break;
      case 6: v = pqW[k * 256 + n]; break;
      default: v = pkW[idx]; break;   // plain row-major copy
    }
  }
  ws[i] = f2bf(v);
}

// 1 workgroup = 4 batches = 80 rows. 4 waves; wave owns a 64-col N-slice.
// Output f32: [oh B*8 | c1 B*10 | c2 B*10 | pl B*20].
template<bool PREPPED>
__global__ __launch_bounds__(256, 2) void fused_graphnet(
    const float* __restrict__ nf, const int* __restrict__ nn_c,
    const float* __restrict__ neW, const float* __restrict__ neb,
    const float* __restrict__ g1W1, const float* __restrict__ g1b1,
    const float* __restrict__ g1W2, const float* __restrict__ g1b2,
    const float* __restrict__ g2W1, const float* __restrict__ g2b1,
    const float* __restrict__ g2W2, const float* __restrict__ g2b2,
    const float* __restrict__ n1g, const float* __restrict__ n1b,
    const float* __restrict__ n2g, const float* __restrict__ n2b,
    const float* __restrict__ ohW, const float* __restrict__ ohb,
    const float* __restrict__ c1W, const float* __restrict__ c1b,
    const float* __restrict__ c2W, const float* __restrict__ c2b,
    const float* __restrict__ pqW, const float* __restrict__ pqb,
    const float* __restrict__ pkW, const float* __restrict__ pkb,
    const ushort_t* __restrict__ ws, float* __restrict__ out,
    int out_n, int Bv)
{
  __shared__ __align__(16) ushort_t hbuf[80 * 256];   // 40KB swizzled bf16
  __shared__ __align__(16) ushort_t smallA[16 * 256]; // 8KB: msg/g/q A-operand
  __shared__ float pbf[4 * 256];                      // pb then r
  __shared__ float gfs[4][256];
  __shared__ float rowstats[4][80][2];
  __shared__ float qdot[4];

  const int b0 = blockIdx.x * 4;
  const int tid = threadIdx.x;
  const int wave = tid >> 6, lane = tid & 63;
  const int lg = lane >> 4, lc = lane & 15;
  const int n0 = wave * 64;

  const int Bout = out_n / 48;
  const int off_c1 = 8 * Bout;
  const int off_c2 = 18 * Bout;
  const int off_pl = 28 * Bout;

  int cnt[4]; float dinv[4];
#pragma unroll
  for (int b = 0; b < 4; b++){
    int bi = b0 + b; if (bi >= Bv) bi = Bv - 1;
    int c = nn_c[bi];
    c = c < 0 ? 0 : (c > 20 ? 20 : c);
    cnt[b] = c;
    dinv[b] = 1.0f / (float)(c < 1 ? 1 : c);
  }

  // zero-init both MFMA-operand LDS buffers; stage nf cols 0..15 (16..31 = K-pad)
  for (int i = tid; i < 80 * 256; i += 256) hbuf[i] = 0;
  for (int i = tid; i < 16 * 256; i += 256) smallA[i] = 0;
  __syncthreads();
  for (int i = tid; i < 80 * 16; i += 256){
    int row = i >> 4, k = i & 15;
    int gr = b0 * 20 + row; if (gr >= Bv * 20) gr = Bv * 20 - 1;
    hbuf[swzi(row, k)] = f2bf(nf[gr * 16 + k]);
  }
  __syncthreads();

  const f32x4 zero4 = {0.0f, 0.0f, 0.0f, 0.0f};

  // GEMM0: hacc = nf @ neW + neb (single K-step of 32)
  f32x4 hacc[5][4];
  {
    short8 a[5], bv[4];
#pragma unroll
    for (int mt = 0; mt < 5; mt++) a[mt] = ldsA(hbuf, mt * 16 + lc, lg * 8);
#pragma unroll
    for (int nt = 0; nt < 4; nt++){
      int n = n0 + nt * 16 + lc;
      if constexpr (PREPPED) bv[nt] = ldG(ws + WS_NEWT + n * 32 + lg * 8);
      else bv[nt] = loadWT16(neW, n, lg * 8);
    }
#pragma unroll
    for (int mt = 0; mt < 5; mt++)
#pragma unroll
      for (int nt = 0; nt < 4; nt++)
        hacc[mt][nt] = MFMA(a[mt], bv[nt], zero4);
#pragma unroll
    for (int nt = 0; nt < 4; nt++){
      float bb = neb[n0 + nt * 16 + lc];
#pragma unroll
      for (int mt = 0; mt < 5; mt++)
#pragma unroll
        for (int r = 0; r < 4; r++) hacc[mt][nt][r] += bb;
    }
  }
  __syncthreads();
#pragma unroll
  for (int mt = 0; mt < 5; mt++)
#pragma unroll
    for (int nt = 0; nt < 4; nt++)
#pragma unroll
      for (int r = 0; r < 4; r++)
        hbuf[swzi(mt * 16 + lg * 4 + r, n0 + nt * 16 + lc)] = f2bf(hacc[mt][nt][r]);
  __syncthreads();

  for (int rd = 0; rd < 2; rd++){
    const int w1at = (rd == 0) ? WS_W1AT1 : WS_W1AT2;
    const int w1bt = (rd == 0) ? WS_W1BT1 : WS_W1BT2;
    const int w2t  = (rd == 0) ? WS_W2T1  : WS_W2T2;
    const float* W1 = (rd == 0) ? g1W1 : g2W1;
    const float* W2 = (rd == 0) ? g1W2 : g2W2;
    const float* b1p = (rd == 0) ? g1b1 : g2b1;
    const float* b2p = (rd == 0) ? g1b2 : g2b2;
    const float* ngp = (rd == 0) ? n1g : n2g;
    const float* nbp = (rd == 0) ? n1b : n2b;

    // masked mean -> smallA rows 0..3 (bf16 msg)
    {
      float s[4] = {0, 0, 0, 0};
      for (int r = 0; r < 20; r++){
#pragma unroll
        for (int b = 0; b < 4; b++)
          if (r < cnt[b]) s[b] += bf2f(hbuf[swzi(b * 20 + r, tid)]);
      }
#pragma unroll
      for (int b = 0; b < 4; b++) smallA[swzi(b, tid)] = f2bf(s[b] * dinv[b]);
    }
    __syncthreads();

    // pb = msg @ W1b + b1 (batch rows 0..3)
    {
      f32x4 acc[4];
#pragma unroll
      for (int nt = 0; nt < 4; nt++) acc[nt] = zero4;
      for (int kk = 0; kk < 8; kk++){
        short8 a = ldsA(smallA, lc, kk * 32 + lg * 8);
#pragma unroll
        for (int nt = 0; nt < 4; nt++){
          int n = n0 + nt * 16 + lc;
          short8 bv;
          if constexpr (PREPPED) bv = ldG(ws + w1bt + n * 256 + kk * 32 + lg * 8);
          else bv = loadWT(W1 + 256 * 256, n, kk * 32 + lg * 8);
          acc[nt] = MFMA(a, bv, acc[nt]);
        }
      }
      if (lg == 0){
#pragma unroll
        for (int nt = 0; nt < 4; nt++)
#pragma unroll
          for (int r = 0; r < 4; r++){
            int col = n0 + nt * 16 + lc;
            pbf[r * 256 + col] = acc[nt][r] + b1p[col];
          }
      }
    }

    // G1: tacc = h @ W1a
    f32x4 tacc[5][4];
#pragma unroll
    for (int mt = 0; mt < 5; mt++)
#pragma unroll
      for (int nt = 0; nt < 4; nt++) tacc[mt][nt] = zero4;
    for (int kk = 0; kk < 8; kk++){
      short8 a[5], bv[4];
#pragma unroll
      for (int mt = 0; mt < 5; mt++) a[mt] = ldsA(hbuf, mt * 16 + lc, kk * 32 + lg * 8);
#pragma unroll
      for (int nt = 0; nt < 4; nt++){
        int n = n0 + nt * 16 + lc;
        if constexpr (PREPPED) bv[nt] = ldG(ws + w1at + n * 256 + kk * 32 + lg * 8);
        else bv[nt] = loadWT(W1, n, kk * 32 + lg * 8);
      }
#pragma unroll
      for (int mt = 0; mt < 5; mt++)
#pragma unroll
        for (int nt = 0; nt < 4; nt++) tacc[mt][nt] = MFMA(a[mt], bv[nt], tacc[mt][nt]);
    }
    __syncthreads();  // all h reads + pbf writes complete

    // t1 = relu(tacc + pb[batch]) -> hbuf
#pragma unroll
    for (int mt = 0; mt < 5; mt++)
#pragma unroll
      for (int nt = 0; nt < 4; nt++)
#pragma unroll
        for (int r = 0; r < 4; r++){
          int row = mt * 16 + lg * 4 + r;
          int col = n0 + nt * 16 + lc;
          float v = tacc[mt][nt][r] + pbf[(row / 20) * 256 + col];
          hbuf[swzi(row, col)] = f2bf(fmaxf(v, 0.0f));
        }
    __syncthreads();

    // hacc += b2; hacc += t1 @ W2
    {
#pragma unroll
      for (int nt = 0; nt < 4; nt++){
        float b2s = b2p[n0 + nt * 16 + lc];
#pragma unroll
        for (int mt = 0; mt < 5; mt++)
#pragma unroll
          for (int r = 0; r < 4; r++) hacc[mt][nt][r] += b2s;
      }
      for (int kk = 0; kk < 8; kk++){
        short8 a[5], bv[4];
#pragma unroll
        for (int mt = 0; mt < 5; mt++) a[mt] = ldsA(hbuf, mt * 16 + lc, kk * 32 + lg * 8);
#pragma unroll
        for (int nt = 0; nt < 4; nt++){
          int n = n0 + nt * 16 + lc;
          if constexpr (PREPPED) bv[nt] = ldG(ws + w2t + n * 256 + kk * 32 + lg * 8);
          else bv[nt] = loadWT(W2, n, kk * 32 + lg * 8);
        }
#pragma unroll
        for (int mt = 0; mt < 5; mt++)
#pragma unroll
          for (int nt = 0; nt < 4; nt++) hacc[mt][nt] = MFMA(a[mt], bv[nt], hacc[mt][nt]);
      }
    }

    // LayerNorm over 256 cols, then *mask
    {
#pragma unroll
      for (int mt = 0; mt < 5; mt++)
#pragma unroll
        for (int r = 0; r < 4; r++){
          int row = mt * 16 + lg * 4 + r;
          float s1 = 0, s2 = 0;
#pragma unroll
          for (int nt = 0; nt < 4; nt++){ float v = hacc[mt][nt][r]; s1 += v; s2 += v * v; }
#pragma unroll
          for (int d = 1; d < 16; d <<= 1){ s1 += __shfl_xor(s1, d, 64); s2 += __shfl_xor(s2, d, 64); }
          if (lc == 0){ rowstats[wave][row][0] = s1; rowstats[wave][row][1] = s2; }
        }
      __syncthreads();  // stats published; all G2 hbuf reads done
      float ngv[4], nbv[4];
#pragma unroll
      for (int nt = 0; nt < 4; nt++){
        ngv[nt] = ngp[n0 + nt * 16 + lc];
        nbv[nt] = nbp[n0 + nt * 16 + lc];
      }
#pragma unroll
      for (int mt = 0; mt < 5; mt++)
#pragma unroll
        for (int r = 0; r < 4; r++){
          int row = mt * 16 + lg * 4 + r;
          float t1s = rowstats[0][row][0] + rowstats[1][row][0] + rowstats[2][row][0] + rowstats[3][row][0];
          float t2s = rowstats[0][row][1] + rowstats[1][row][1] + rowstats[2][row][1] + rowstats[3][row][1];
          float mean = t1s * (1.0f / 256.0f);
          float var  = t2s * (1.0f / 256.0f) - mean * mean;
          float rstd = rsqrtf(fmaxf(var, 0.0f) + 1e-5f);
          int bb = row / 20;
          float mf = ((row - bb * 20) < cnt[bb]) ? 1.0f : 0.0f;
#pragma unroll
          for (int nt = 0; nt < 4; nt++){
            int col = n0 + nt * 16 + lc;
            float v = ((hacc[mt][nt][r] - mean) * rstd * ngv[nt] + nbv[nt]) * mf;
            hacc[mt][nt][r] = v;
            hbuf[swzi(row, col)] = f2bf(v);
          }
        }
    }
    __syncthreads();
  }

  // g = masked mean -> gfs (f32) + smallA rows 0..3 (bf16)
  {
    float s[4] = {0, 0, 0, 0};
    for (int r = 0; r < 20; r++){
#pragma unroll
      for (int b = 0; b < 4; b++)
        if (r < cnt[b]) s[b] += bf2f(hbuf[swzi(b * 20 + r, tid)]);
    }
#pragma unroll
    for (int b = 0; b < 4; b++){
      float v = s[b] * dinv[b];
      gfs[b][tid] = v;
      smallA[swzi(b, tid)] = f2bf(v);
    }
  }
  __syncthreads();

  // q = g @ pqW + pqb -> smallA rows 0..3
  {
    f32x4 qacc[4];
#pragma unroll
    for (int nt = 0; nt < 4; nt++) qacc[nt] = zero4;
    for (int kk = 0; kk < 8; kk++){
      short8 a = ldsA(smallA, lc, kk * 32 + lg * 8);
#pragma unroll
      for (int nt = 0; nt < 4; nt++){
        int n = n0 + nt * 16 + lc;
        short8 bv;
        if constexpr (PREPPED) bv = ldG(ws + WS_PQWT + n * 256 + kk * 32 + lg * 8);
        else bv = loadWT(pqW, n, kk * 32 + lg * 8);
        qacc[nt] = MFMA(a, bv, qacc[nt]);
      }
    }
    __syncthreads();  // g reads done before q overwrite
    if (lg == 0){
#pragma unroll
      for (int nt = 0; nt < 4; nt++)
#pragma unroll
        for (int r = 0; r < 4; r++){
          int col = n0 + nt * 16 + lc;
          smallA[swzi(r, col)] = f2bf(qacc[nt][r] + pqb[col]);
        }
    }
    __syncthreads();
  }

  // qdot[b] = q[b].pkb (wave w = batch w; q bf16 from smallA)
  {
    float p = 0;
#pragma unroll
    for (int j = 0; j < 4; j++){
      int hh = lane * 4 + j;
      p += bf2f(smallA[swzi(wave, hh)]) * pkb[hh];
    }
#pragma unroll
    for (int d = 1; d < 64; d <<= 1) p += __shfl_xor(p, d, 64);
    if (lane == 0) qdot[wave] = p;
  }

  // r[b][n] = sum_k q[b][k]*pkW[n][k] -> pbf
  {
    f32x4 racc[4];
#pragma unroll
    for (int nt = 0; nt < 4; nt++) racc[nt] = zero4;
    for (int kk = 0; kk < 8; kk++){
      short8 a = ldsA(smallA, lc, kk * 32 + lg * 8);
#pragma unroll
      for (int nt = 0; nt < 4; nt++){
        int n = n0 + nt * 16 + lc;
        short8 bv;
        if constexpr (PREPPED) bv = ldG(ws + WS_PKWP + n * 256 + kk * 32 + lg * 8);
        else bv = loadWrow(pkW, n, kk * 32 + lg * 8);
        racc[nt] = MFMA(a, bv, racc[nt]);
      }
    }
    if (lg == 0){
#pragma unroll
      for (int nt = 0; nt < 4; nt++)
#pragma unroll
        for (int r = 0; r < 4; r++)
          pbf[r * 256 + (n0 + nt * 16 + lc)] = racc[nt][r];
    }
  }
  __syncthreads();

  // pl[b,n] = h[row].r[b] + qdot[b] (masked -> exactly -1e9); wave w = batch w
  {
    const int b = wave;
    if (b0 + b < Bv){
      for (int rr = 0; rr < 20; rr++){
        int row = b * 20 + rr;
        const ushort_t* hp = hbuf + swzi(row, lane * 4);
        const float* rp = pbf + b * 256 + lane * 4;
        float p = bf2f(hp[0]) * rp[0] + bf2f(hp[1]) * rp[1] + bf2f(hp[2]) * rp[2] + bf2f(hp[3]) * rp[3];
#pragma unroll
        for (int d = 1; d < 64; d <<= 1) p += __shfl_xor(p, d, 64);
        if (lane == 0){
          float v = (rr < cnt[b]) ? (p + qdot[b]) : -1e9f;
          out[off_pl + (b0 + b) * 20 + rr] = v;
        }
      }
    }
  }

  // heads (wave w = batch w): oh [B,8]@0, c1 [B,10]@off_c1, c2 [B,10]@off_c2
  {
    const int b = wave;
    if (b0 + b < Bv){
      for (int o = 0; o < 28; o++){
        const float* W; const float* bias; int ncol, col, off;
        if (o < 8)      { W = ohW; bias = ohb; ncol = 8;  col = o;      off = 0; }
        else if (o < 18){ W = c1W; bias = c1b; ncol = 10; col = o - 8;  off = off_c1; }
        else            { W = c2W; bias = c2b; ncol = 10; col = o - 18; off = off_c2; }
        float p = 0;
#pragma unroll
        for (int j = 0; j < 4; j++){
          int k = lane * 4 + j;
          p += gfs[b][k] * W[k * ncol + col];
        }
#pragma unroll
        for (int d = 1; d < 64; d <<= 1) p += __shfl_xor(p, d, 64);
        if (lane == 0) out[off + (b0 + b) * ncol + col] = p + bias[col];
      }
    }
  }
}

extern "C" void kernel_launch(void* const* d_in, const int* in_sizes, int n_in,
                              void* d_out, int out_size, void* d_ws, size_t ws_size,
                              hipStream_t stream)
{
  const float* nf   = (const float*)d_in[0];
  const int*   nn_c = (const int*)d_in[1];
  const float* neW  = (const float*)d_in[2];
  const float* neb  = (const float*)d_in[3];
  const float* g1W1 = (const float*)d_in[4];
  const float* g1b1 = (const float*)d_in[5];
  const float* g1W2 = (const float*)d_in[6];
  const float* g1b2 = (const float*)d_in[7];
  const float* g2W1 = (const float*)d_in[8];
  const float* g2b1 = (const float*)d_in[9];
  const float* g2W2 = (const float*)d_in[10];
  const float* g2b2 = (const float*)d_in[11];
  const float* n1g  = (const float*)d_in[12];
  const float* n1b  = (const float*)d_in[13];
  const float* n2g  = (const float*)d_in[14];
  const float* n2b  = (const float*)d_in[15];
  const float* ohW  = (const float*)d_in[16];
  const float* ohb  = (const float*)d_in[17];
  const float* c1W  = (const float*)d_in[18];
  const float* c1b  = (const float*)d_in[19];
  const float* c2W  = (const float*)d_in[20];
  const float* c2b  = (const float*)d_in[21];
  const float* pqW  = (const float*)d_in[22];
  const float* pqb  = (const float*)d_in[23];
  const float* pkW  = (const float*)d_in[24];
  const float* pkb  = (const float*)d_in[25];

  float* outp = (float*)d_out;
  ushort_t* ws = (ushort_t*)d_ws;
  int B = in_sizes[0] / 320;       // nf is [B,20,16]
  int grid = (B + 3) / 4;

  if (ws_size >= (size_t)WS_BYTES){
    prep_weights<<<(WS_TOTAL + 255) / 256, 256, 0, stream>>>(
        neW, g1W1, g1W2, g2W1, g2W2, pqW, pkW, ws);
    fused_graphnet<true><<<grid, 256, 0, stream>>>(
        nf, nn_c, neW, neb, g1W1, g1b1, g1W2, g1b2, g2W1, g2b1, g2W2, g2b2,
        n1g, n1b, n2g, n2b, ohW, ohb, c1W, c1b, c2W, c2b, pqW, pqb, pkW, pkb,
        ws, outp, out_size, B);
  } else {
    fused_graphnet<false><<<grid, 256, 0, stream>>>(
        nf, nn_c, neW, neb, g1W1, g1b1, g1W2, g1b2, g2W1, g2b1, g2W2, g2b2,
        n1g, n1b, n2g, n2b, ohW, ohb, c1W, c1b, c2W, c2b, pqW, pqb, pkW, pkb,
        ws, outp, out_size, B);
  }
}

// Round 7
// 1211.164 us; speedup vs baseline: 4.4861x; 1.6670x over previous
//
#include <hip/hip_runtime.h>

typedef unsigned short ushort_t;
using short8  = __attribute__((ext_vector_type(8))) short;
using short4v = __attribute__((ext_vector_type(4))) short;
using f32x4   = __attribute__((ext_vector_type(4))) float;

#define DI __device__ __forceinline__

DI ushort_t f2bf(float f){
  union { float f; unsigned u; } v; v.f = f;
  unsigned u = v.u;
  return (ushort_t)((u + 0x7FFFu + ((u >> 16) & 1u)) >> 16);
}
DI float bf2f(ushort_t u){
  union { unsigned u; float f; } v; v.u = ((unsigned)u) << 16;
  return v.f;
}

DI f32x4 MFMA(short8 a, short8 b, f32x4 c){
  return __builtin_amdgcn_mfma_f32_16x16x32_bf16(a, b, c, 0, 0, 0);
}

// swizzled LDS bf16 tile addressing; row stride 256 elems (512B)
DI int swzi(int row, int col){
  int byte = (row << 9) + (col << 1);
  byte ^= (row & 7) << 4;
  return byte >> 1;
}
DI short8 ldsA(const ushort_t* buf, int row, int k0){
  return *(const short8*)(buf + swzi(row, k0));
}
DI short8 ldG(const ushort_t* p){ return *(const short8*)p; }

// fallback B-fragment builders from f32 global (used when ws too small)
DI short8 loadWT(const float* __restrict__ W, int n, int k0){
  short8 s;
#pragma unroll
  for (int j = 0; j < 8; j++) s[j] = (short)f2bf(W[(k0 + j) * 256 + n]);
  return s;
}
DI short8 loadWT16(const float* __restrict__ W, int n, int k0){
  short8 s;
#pragma unroll
  for (int j = 0; j < 8; j++){
    int k = k0 + j;
    s[j] = (short)((k < 16) ? f2bf(W[k * 256 + n]) : 0);
  }
  return s;
}
DI short8 loadWrow(const float* __restrict__ W, int n, int k0){
  short8 s;
#pragma unroll
  for (int j = 0; j < 8; j++) s[j] = (short)f2bf(W[n * 256 + k0 + j]);
  return s;
}

// d_ws layout (ushort indices)
#define WS_NEWT  0        // [256][32]  neW^T, K padded 16->32
#define WS_W1AT1 8192     // [256][256] g1W1[0:256]^T
#define WS_W1BT1 73728    // [256][256] g1W1[256:512]^T
#define WS_W2T1  139264   // [256][256] g1W2^T
#define WS_W1AT2 204800
#define WS_W1BT2 270336
#define WS_W2T2  335872
#define WS_PQWT  401408   // [256][256] pqW^T
#define WS_PKWP  466944   // [256][256] pkW plain copy (acts as B^T for r-GEMM)
#define WS_TOTAL 532480
#define WS_BYTES (WS_TOTAL * 2)

__global__ void prep_weights(
    const float* __restrict__ neW, const float* __restrict__ g1W1,
    const float* __restrict__ g1W2, const float* __restrict__ g2W1,
    const float* __restrict__ g2W2, const float* __restrict__ pqW,
    const float* __restrict__ pkW, ushort_t* __restrict__ ws)
{
  int i = blockIdx.x * 256 + threadIdx.x;
  if (i >= WS_TOTAL) return;
  float v;
  if (i < 8192){
    int n = i >> 5, k = i & 31;
    v = (k < 16) ? neW[k * 256 + n] : 0.0f;
  } else {
    int j = i - 8192;
    int region = j >> 16;
    int idx = j & 65535;
    int n = idx >> 8, k = idx & 255;
    switch (region){
      case 0: v = g1W1[k * 256 + n]; break;
      case 1: v = g1W1[(256 + k) * 256 + n]; break;
      case 2: v = g1W2[k * 256 + n]; break;
      case 3: v = g2W1[k * 256 + n]; break;
      case 4: v = g2W1[(256 + k) * 256 + n]; break;
      case 5: v = g2W2[k * 256 + n]; break;
      case 6: v = pqW[k * 256 + n]; break;
      default: v = pkW[idx]; break;   // plain row-major copy
    }
  }
  ws[i] = f2bf(v);
}

// 1 workgroup = 4 batches = 80 rows. 4 waves; wave owns a 64-col N-slice.
// Output f32: [oh B*8 | c1 B*10 | c2 B*10 | pl B*20].
template<bool PREPPED>
__global__ __launch_bounds__(256, 1) void fused_graphnet(
    const float* __restrict__ nf, const int* __restrict__ nn_c,
    const float* __restrict__ neW, const float* __restrict__ neb,
    const float* __restrict__ g1W1, const float* __restrict__ g1b1,
    const float* __restrict__ g1W2, const float* __restrict__ g1b2,
    const float* __restrict__ g2W1, const float* __restrict__ g2b1,
    const float* __restrict__ g2W2, const float* __restrict__ g2b2,
    const float* __restrict__ n1g, const float* __restrict__ n1b,
    const float* __restrict__ n2g, const float* __restrict__ n2b,
    const float* __restrict__ ohW, const float* __restrict__ ohb,
    const float* __restrict__ c1W, const float* __restrict__ c1b,
    const float* __restrict__ c2W, const float* __restrict__ c2b,
    const float* __restrict__ pqW, const float* __restrict__ pqb,
    const float* __restrict__ pkW, const float* __restrict__ pkb,
    const ushort_t* __restrict__ ws, float* __restrict__ out,
    int out_n, int Bv)
{
  __shared__ __align__(16) ushort_t hbuf[80 * 256];  // 40KB swizzled bf16
  __shared__ __align__(16) ushort_t smallA[8 * 256]; // 4KB: msg/g rows 0..3, q rows 4..7
  __shared__ float pbf[4 * 256];                     // pb then r
  __shared__ float rowstats[4][80][2];
  __shared__ float qdot[4];
  __shared__ int   cntS[4];
  __shared__ float dinvS[4];

  const int b0 = blockIdx.x * 4;
  const int tid = threadIdx.x;
  const int wave = tid >> 6, lane = tid & 63;
  const int lg = lane >> 4, lc = lane & 15;
  const int n0 = wave * 64;

  const int Bout = out_n / 48;
  const int off_c1 = 8 * Bout;
  const int off_c2 = 18 * Bout;
  const int off_pl = 28 * Bout;

  if (tid < 4){
    int bi = b0 + tid; if (bi >= Bv) bi = Bv - 1;
    int c = nn_c[bi];
    c = c < 0 ? 0 : (c > 20 ? 20 : c);
    cntS[tid] = c;
    dinvS[tid] = 1.0f / (float)(c < 1 ? 1 : c);
  }

  // zero K-pad cols 16..31 (rows 0..79) and stage nf cols 0..15 (disjoint)
  for (int i = tid; i < 80 * 4; i += 256){   // short4 zero writes
    int row = i >> 2, c0 = 16 + (i & 3) * 4;
    *(short4v*)(hbuf + swzi(row, c0)) = (short4v){0, 0, 0, 0};
  }
  for (int i = tid; i < 80 * 16; i += 256){
    int row = i >> 4, k = i & 15;
    int gr = b0 * 20 + row; if (gr >= Bv * 20) gr = Bv * 20 - 1;
    hbuf[swzi(row, k)] = f2bf(nf[gr * 16 + k]);
  }
  __syncthreads();

  const f32x4 zero4 = {0.0f, 0.0f, 0.0f, 0.0f};

  // GEMM0: hacc = nf @ neW + neb (single K-step of 32)
  f32x4 hacc[5][4];
  {
    short8 a[5], bv[4];
#pragma unroll
    for (int mt = 0; mt < 5; mt++) a[mt] = ldsA(hbuf, mt * 16 + lc, lg * 8);
#pragma unroll
    for (int nt = 0; nt < 4; nt++){
      int n = n0 + nt * 16 + lc;
      if constexpr (PREPPED) bv[nt] = ldG(ws + WS_NEWT + n * 32 + lg * 8);
      else bv[nt] = loadWT16(neW, n, lg * 8);
    }
#pragma unroll
    for (int mt = 0; mt < 5; mt++)
#pragma unroll
      for (int nt = 0; nt < 4; nt++)
        hacc[mt][nt] = MFMA(a[mt], bv[nt], zero4);
#pragma unroll
    for (int nt = 0; nt < 4; nt++){
      float bb = neb[n0 + nt * 16 + lc];
#pragma unroll
      for (int mt = 0; mt < 5; mt++)
#pragma unroll
        for (int r = 0; r < 4; r++) hacc[mt][nt][r] += bb;
    }
  }
  __syncthreads();
#pragma unroll
  for (int mt = 0; mt < 5; mt++)
#pragma unroll
    for (int nt = 0; nt < 4; nt++)
#pragma unroll
      for (int r = 0; r < 4; r++)
        hbuf[swzi(mt * 16 + lg * 4 + r, n0 + nt * 16 + lc)] = f2bf(hacc[mt][nt][r]);
  __syncthreads();

  for (int rd = 0; rd < 2; rd++){
    const int w1at = (rd == 0) ? WS_W1AT1 : WS_W1AT2;
    const int w1bt = (rd == 0) ? WS_W1BT1 : WS_W1BT2;
    const int w2t  = (rd == 0) ? WS_W2T1  : WS_W2T2;
    const float* W1 = (rd == 0) ? g1W1 : g2W1;
    const float* W2 = (rd == 0) ? g1W2 : g2W2;
    const float* b1p = (rd == 0) ? g1b1 : g2b1;
    const float* b2p = (rd == 0) ? g1b2 : g2b2;
    const float* ngp = (rd == 0) ? n1g : n2g;
    const float* nbp = (rd == 0) ? n1b : n2b;

    // masked mean -> smallA rows 0..3 (bf16 msg); thread: batch tid>>6, cols 4*(tid&63)
    {
      int b = tid >> 6;
      int c0 = (tid & 63) * 4;
      int c = cntS[b];
      float s0 = 0, s1 = 0, s2 = 0, s3 = 0;
      for (int r = 0; r < c; r++){
        short4v v = *(const short4v*)(hbuf + swzi(b * 20 + r, c0));
        s0 += bf2f((ushort_t)v[0]); s1 += bf2f((ushort_t)v[1]);
        s2 += bf2f((ushort_t)v[2]); s3 += bf2f((ushort_t)v[3]);
      }
      float di = dinvS[b];
      short4v o;
      o[0] = (short)f2bf(s0 * di); o[1] = (short)f2bf(s1 * di);
      o[2] = (short)f2bf(s2 * di); o[3] = (short)f2bf(s3 * di);
      *(short4v*)(smallA + swzi(b, c0)) = o;
    }
    __syncthreads();

    // pb = msg @ W1b + b1 (batch rows 0..3); 2-stage B prefetch
    {
      f32x4 acc[4];
#pragma unroll
      for (int nt = 0; nt < 4; nt++) acc[nt] = zero4;
      short8 bv0[4], bv1[4];
#pragma unroll
      for (int nt = 0; nt < 4; nt++){
        int n = n0 + nt * 16 + lc;
        if constexpr (PREPPED) bv0[nt] = ldG(ws + w1bt + n * 256 + lg * 8);
        else bv0[nt] = loadWT(W1 + 256 * 256, n, lg * 8);
      }
#pragma unroll
      for (int kk = 0; kk < 8; kk++){
        if (kk < 7){
#pragma unroll
          for (int nt = 0; nt < 4; nt++){
            int n = n0 + nt * 16 + lc;
            short8 nb;
            if constexpr (PREPPED) nb = ldG(ws + w1bt + n * 256 + (kk + 1) * 32 + lg * 8);
            else nb = loadWT(W1 + 256 * 256, n, (kk + 1) * 32 + lg * 8);
            if (kk & 1) bv0[nt] = nb; else bv1[nt] = nb;
          }
        }
        short8 a = ldsA(smallA, lc & 3, kk * 32 + lg * 8);
#pragma unroll
        for (int nt = 0; nt < 4; nt++)
          acc[nt] = MFMA(a, (kk & 1) ? bv1[nt] : bv0[nt], acc[nt]);
      }
      if (lg == 0){
#pragma unroll
        for (int nt = 0; nt < 4; nt++)
#pragma unroll
          for (int r = 0; r < 4; r++){
            int col = n0 + nt * 16 + lc;
            pbf[r * 256 + col] = acc[nt][r] + b1p[col];
          }
      }
    }

    // G1: tacc = h @ W1a ; 2-stage B prefetch
    f32x4 tacc[5][4];
#pragma unroll
    for (int mt = 0; mt < 5; mt++)
#pragma unroll
      for (int nt = 0; nt < 4; nt++) tacc[mt][nt] = zero4;
    {
      short8 bv0[4], bv1[4];
#pragma unroll
      for (int nt = 0; nt < 4; nt++){
        int n = n0 + nt * 16 + lc;
        if constexpr (PREPPED) bv0[nt] = ldG(ws + w1at + n * 256 + lg * 8);
        else bv0[nt] = loadWT(W1, n, lg * 8);
      }
#pragma unroll
      for (int kk = 0; kk < 8; kk++){
        if (kk < 7){
#pragma unroll
          for (int nt = 0; nt < 4; nt++){
            int n = n0 + nt * 16 + lc;
            short8 nb;
            if constexpr (PREPPED) nb = ldG(ws + w1at + n * 256 + (kk + 1) * 32 + lg * 8);
            else nb = loadWT(W1, n, (kk + 1) * 32 + lg * 8);
            if (kk & 1) bv0[nt] = nb; else bv1[nt] = nb;
          }
        }
        short8 a[5];
#pragma unroll
        for (int mt = 0; mt < 5; mt++) a[mt] = ldsA(hbuf, mt * 16 + lc, kk * 32 + lg * 8);
#pragma unroll
        for (int mt = 0; mt < 5; mt++)
#pragma unroll
          for (int nt = 0; nt < 4; nt++)
            tacc[mt][nt] = MFMA(a[mt], (kk & 1) ? bv1[nt] : bv0[nt], tacc[mt][nt]);
      }
    }
    __syncthreads();  // all h reads + pbf writes complete

    // t1 = relu(tacc + pb[batch]) -> hbuf
#pragma unroll
    for (int mt = 0; mt < 5; mt++)
#pragma unroll
      for (int nt = 0; nt < 4; nt++)
#pragma unroll
        for (int r = 0; r < 4; r++){
          int row = mt * 16 + lg * 4 + r;
          int col = n0 + nt * 16 + lc;
          float v = tacc[mt][nt][r] + pbf[(row / 20) * 256 + col];
          hbuf[swzi(row, col)] = f2bf(fmaxf(v, 0.0f));
        }
    __syncthreads();

    // hacc += b2; hacc += t1 @ W2 ; 2-stage B prefetch
    {
#pragma unroll
      for (int nt = 0; nt < 4; nt++){
        float b2s = b2p[n0 + nt * 16 + lc];
#pragma unroll
        for (int mt = 0; mt < 5; mt++)
#pragma unroll
          for (int r = 0; r < 4; r++) hacc[mt][nt][r] += b2s;
      }
      short8 bv0[4], bv1[4];
#pragma unroll
      for (int nt = 0; nt < 4; nt++){
        int n = n0 + nt * 16 + lc;
        if constexpr (PREPPED) bv0[nt] = ldG(ws + w2t + n * 256 + lg * 8);
        else bv0[nt] = loadWT(W2, n, lg * 8);
      }
#pragma unroll
      for (int kk = 0; kk < 8; kk++){
        if (kk < 7){
#pragma unroll
          for (int nt = 0; nt < 4; nt++){
            int n = n0 + nt * 16 + lc;
            short8 nb;
            if constexpr (PREPPED) nb = ldG(ws + w2t + n * 256 + (kk + 1) * 32 + lg * 8);
            else nb = loadWT(W2, n, (kk + 1) * 32 + lg * 8);
            if (kk & 1) bv0[nt] = nb; else bv1[nt] = nb;
          }
        }
        short8 a[5];
#pragma unroll
        for (int mt = 0; mt < 5; mt++) a[mt] = ldsA(hbuf, mt * 16 + lc, kk * 32 + lg * 8);
#pragma unroll
        for (int mt = 0; mt < 5; mt++)
#pragma unroll
          for (int nt = 0; nt < 4; nt++)
            hacc[mt][nt] = MFMA(a[mt], (kk & 1) ? bv1[nt] : bv0[nt], hacc[mt][nt]);
      }
    }

    // LayerNorm over 256 cols, then *mask
    {
#pragma unroll
      for (int mt = 0; mt < 5; mt++)
#pragma unroll
        for (int r = 0; r < 4; r++){
          int row = mt * 16 + lg * 4 + r;
          float s1 = 0, s2 = 0;
#pragma unroll
          for (int nt = 0; nt < 4; nt++){ float v = hacc[mt][nt][r]; s1 += v; s2 += v * v; }
#pragma unroll
          for (int d = 1; d < 16; d <<= 1){ s1 += __shfl_xor(s1, d, 64); s2 += __shfl_xor(s2, d, 64); }
          if (lc == 0){ rowstats[wave][row][0] = s1; rowstats[wave][row][1] = s2; }
        }
      __syncthreads();  // stats published; all G2 hbuf reads done
      float ngv[4], nbv[4];
#pragma unroll
      for (int nt = 0; nt < 4; nt++){
        ngv[nt] = ngp[n0 + nt * 16 + lc];
        nbv[nt] = nbp[n0 + nt * 16 + lc];
      }
#pragma unroll
      for (int mt = 0; mt < 5; mt++)
#pragma unroll
        for (int r = 0; r < 4; r++){
          int row = mt * 16 + lg * 4 + r;
          float t1s = rowstats[0][row][0] + rowstats[1][row][0] + rowstats[2][row][0] + rowstats[3][row][0];
          float t2s = rowstats[0][row][1] + rowstats[1][row][1] + rowstats[2][row][1] + rowstats[3][row][1];
          float mean = t1s * (1.0f / 256.0f);
          float var  = t2s * (1.0f / 256.0f) - mean * mean;
          float rstd = rsqrtf(fmaxf(var, 0.0f) + 1e-5f);
          int bb = row / 20;
          float mf = ((row - bb * 20) < cntS[bb]) ? 1.0f : 0.0f;
#pragma unroll
          for (int nt = 0; nt < 4; nt++){
            int col = n0 + nt * 16 + lc;
            float v = ((hacc[mt][nt][r] - mean) * rstd * ngv[nt] + nbv[nt]) * mf;
            hacc[mt][nt][r] = v;
            hbuf[swzi(row, col)] = f2bf(v);
          }
        }
    }
    __syncthreads();
  }

  // g = masked mean -> smallA rows 0..3 (bf16)
  {
    int b = tid >> 6;
    int c0 = (tid & 63) * 4;
    int c = cntS[b];
    float s0 = 0, s1 = 0, s2 = 0, s3 = 0;
    for (int r = 0; r < c; r++){
      short4v v = *(const short4v*)(hbuf + swzi(b * 20 + r, c0));
      s0 += bf2f((ushort_t)v[0]); s1 += bf2f((ushort_t)v[1]);
      s2 += bf2f((ushort_t)v[2]); s3 += bf2f((ushort_t)v[3]);
    }
    float di = dinvS[b];
    short4v o;
    o[0] = (short)f2bf(s0 * di); o[1] = (short)f2bf(s1 * di);
    o[2] = (short)f2bf(s2 * di); o[3] = (short)f2bf(s3 * di);
    *(short4v*)(smallA + swzi(b, c0)) = o;
  }
  __syncthreads();

  // q = g @ pqW + pqb -> smallA rows 4..7 (disjoint from read rows; no barrier inside)
  {
    f32x4 qacc[4];
#pragma unroll
    for (int nt = 0; nt < 4; nt++) qacc[nt] = zero4;
    short8 bv0[4], bv1[4];
#pragma unroll
    for (int nt = 0; nt < 4; nt++){
      int n = n0 + nt * 16 + lc;
      if constexpr (PREPPED) bv0[nt] = ldG(ws + WS_PQWT + n * 256 + lg * 8);
      else bv0[nt] = loadWT(pqW, n, lg * 8);
    }
#pragma unroll
    for (int kk = 0; kk < 8; kk++){
      if (kk < 7){
#pragma unroll
        for (int nt = 0; nt < 4; nt++){
          int n = n0 + nt * 16 + lc;
          short8 nb;
          if constexpr (PREPPED) nb = ldG(ws + WS_PQWT + n * 256 + (kk + 1) * 32 + lg * 8);
          else nb = loadWT(pqW, n, (kk + 1) * 32 + lg * 8);
          if (kk & 1) bv0[nt] = nb; else bv1[nt] = nb;
        }
      }
      short8 a = ldsA(smallA, lc & 3, kk * 32 + lg * 8);
#pragma unroll
      for (int nt = 0; nt < 4; nt++)
        qacc[nt] = MFMA(a, (kk & 1) ? bv1[nt] : bv0[nt], qacc[nt]);
    }
    if (lg == 0){
#pragma unroll
      for (int nt = 0; nt < 4; nt++)
#pragma unroll
        for (int r = 0; r < 4; r++){
          int col = n0 + nt * 16 + lc;
          smallA[swzi(4 + r, col)] = f2bf(qacc[nt][r] + pqb[col]);
        }
    }
  }
  __syncthreads();

  // qdot[b] = q[b].pkb (wave w = batch w; q bf16 from smallA rows 4..7)
  {
    short4v qv = *(const short4v*)(smallA + swzi(4 + wave, lane * 4));
    float p = bf2f((ushort_t)qv[0]) * pkb[lane * 4 + 0]
            + bf2f((ushort_t)qv[1]) * pkb[lane * 4 + 1]
            + bf2f((ushort_t)qv[2]) * pkb[lane * 4 + 2]
            + bf2f((ushort_t)qv[3]) * pkb[lane * 4 + 3];
#pragma unroll
    for (int d = 1; d < 64; d <<= 1) p += __shfl_xor(p, d, 64);
    if (lane == 0) qdot[wave] = p;
  }

  // r[b][n] = sum_k q[b][k]*pkW[n][k] -> pbf
  {
    f32x4 racc[4];
#pragma unroll
    for (int nt = 0; nt < 4; nt++) racc[nt] = zero4;
    short8 bv0[4], bv1[4];
#pragma unroll
    for (int nt = 0; nt < 4; nt++){
      int n = n0 + nt * 16 + lc;
      if constexpr (PREPPED) bv0[nt] = ldG(ws + WS_PKWP + n * 256 + lg * 8);
      else bv0[nt] = loadWrow(pkW, n, lg * 8);
    }
#pragma unroll
    for (int kk = 0; kk < 8; kk++){
      if (kk < 7){
#pragma unroll
        for (int nt = 0; nt < 4; nt++){
          int n = n0 + nt * 16 + lc;
          short8 nb;
          if constexpr (PREPPED) nb = ldG(ws + WS_PKWP + n * 256 + (kk + 1) * 32 + lg * 8);
          else nb = loadWrow(pkW, n, (kk + 1) * 32 + lg * 8);
          if (kk & 1) bv0[nt] = nb; else bv1[nt] = nb;
        }
      }
      short8 a = ldsA(smallA, 4 + (lc & 3), kk * 32 + lg * 8);
#pragma unroll
      for (int nt = 0; nt < 4; nt++)
        racc[nt] = MFMA(a, (kk & 1) ? bv1[nt] : bv0[nt], racc[nt]);
    }
    if (lg == 0){
#pragma unroll
      for (int nt = 0; nt < 4; nt++)
#pragma unroll
        for (int r = 0; r < 4; r++)
          pbf[r * 256 + (n0 + nt * 16 + lc)] = racc[nt][r];
    }
  }
  __syncthreads();

  // pl[b,n] = h[row].r[b] + qdot[b] (masked -> exactly -1e9); wave w = batch w
  {
    const int b = wave;
    if (b0 + b < Bv){
      int cb = cntS[b];
      float qd = qdot[b];
      for (int rr = 0; rr < 20; rr++){
        int row = b * 20 + rr;
        short4v hv = *(const short4v*)(hbuf + swzi(row, lane * 4));
        const float* rp = pbf + b * 256 + lane * 4;
        float p = bf2f((ushort_t)hv[0]) * rp[0] + bf2f((ushort_t)hv[1]) * rp[1]
                + bf2f((ushort_t)hv[2]) * rp[2] + bf2f((ushort_t)hv[3]) * rp[3];
#pragma unroll
        for (int d = 1; d < 64; d <<= 1) p += __shfl_xor(p, d, 64);
        if (lane == 0){
          float v = (rr < cb) ? (p + qd) : -1e9f;
          out[off_pl + (b0 + b) * 20 + rr] = v;
        }
      }
    }
  }

  // heads (wave w = batch w): oh [B,8]@0, c1 [B,10]@off_c1, c2 [B,10]@off_c2
  {
    const int b = wave;
    if (b0 + b < Bv){
      short4v gv = *(const short4v*)(smallA + swzi(b, lane * 4));
      float g0 = bf2f((ushort_t)gv[0]), g1 = bf2f((ushort_t)gv[1]);
      float g2 = bf2f((ushort_t)gv[2]), g3 = bf2f((ushort_t)gv[3]);
#pragma unroll
      for (int o = 0; o < 28; o++){
        const float* W; const float* bias; int ncol, col, off;
        if (o < 8)      { W = ohW; bias = ohb; ncol = 8;  col = o;      off = 0; }
        else if (o < 18){ W = c1W; bias = c1b; ncol = 10; col = o - 8;  off = off_c1; }
        else            { W = c2W; bias = c2b; ncol = 10; col = o - 18; off = off_c2; }
        int k = lane * 4;
        float p = g0 * W[(k + 0) * ncol + col] + g1 * W[(k + 1) * ncol + col]
                + g2 * W[(k + 2) * ncol + col] + g3 * W[(k + 3) * ncol + col];
#pragma unroll
        for (int d = 1; d < 64; d <<= 1) p += __shfl_xor(p, d, 64);
        if (lane == 0) out[off + (b0 + b) * ncol + col] = p + bias[col];
      }
    }
  }
}

extern "C" void kernel_launch(void* const* d_in, const int* in_sizes, int n_in,
                              void* d_out, int out_size, void* d_ws, size_t ws_size,
                              hipStream_t stream)
{
  const float* nf   = (const float*)d_in[0];
  const int*   nn_c = (const int*)d_in[1];
  const float* neW  = (const float*)d_in[2];
  const float* neb  = (const float*)d_in[3];
  const float* g1W1 = (const float*)d_in[4];
  const float* g1b1 = (const float*)d_in[5];
  const float* g1W2 = (const float*)d_in[6];
  const float* g1b2 = (const float*)d_in[7];
  const float* g2W1 = (const float*)d_in[8];
  const float* g2b1 = (const float*)d_in[9];
  const float* g2W2 = (const float*)d_in[10];
  const float* g2b2 = (const float*)d_in[11];
  const float* n1g  = (const float*)d_in[12];
  const float* n1b  = (const float*)d_in[13];
  const float* n2g  = (const float*)d_in[14];
  const float* n2b  = (const float*)d_in[15];
  const float* ohW  = (const float*)d_in[16];
  const float* ohb  = (const float*)d_in[17];
  const float* c1W  = (const float*)d_in[18];
  const float* c1b  = (const float*)d_in[19];
  const float* c2W  = (const float*)d_in[20];
  const float* c2b  = (const float*)d_in[21];
  const float* pqW  = (const float*)d_in[22];
  const float* pqb  = (const float*)d_in[23];
  const float* pkW  = (const float*)d_in[24];
  const float* pkb  = (const float*)d_in[25];

  float* outp = (float*)d_out;
  ushort_t* ws = (ushort_t*)d_ws;
  int B = in_sizes[0] / 320;       // nf is [B,20,16]
  int grid = (B + 3) / 4;

  if (ws_size >= (size_t)WS_BYTES){
    prep_weights<<<(WS_TOTAL + 255) / 256, 256, 0, stream>>>(
        neW, g1W1, g1W2, g2W1, g2W2, pqW, pkW, ws);
    fused_graphnet<true><<<grid, 256, 0, stream>>>(
        nf, nn_c, neW, neb, g1W1, g1b1, g1W2, g1b2, g2W1, g2b1, g2W2, g2b2,
        n1g, n1b, n2g, n2b, ohW, ohb, c1W, c1b, c2W, c2b, pqW, pqb, pkW, pkb,
        ws, outp, out_size, B);
  } else {
    fused_graphnet<false><<<grid, 256, 0, stream>>>(
        nf, nn_c, neW, neb, g1W1, g1b1, g1W2, g1b2, g2W1, g2b1, g2W2, g2b2,
        n1g, n1b, n2g, n2b, ohW, ohb, c1W, c1b, c2W, c2b, pqW, pqb, pkW, pkb,
        ws, outp, out_size, B);
  }
}